// Round 2
// baseline (3727.782 us; speedup 1.0000x reference)
//
#include <hip/hip_runtime.h>
#include <math.h>

#define BB 2
#define HH 96
#define WW 160
#define HW (HH*WW)

// Generic 3x3 conv, stride 1, pad 1.
// IN_MODE 0: plain NCHW input with Cin channels.
// IN_MODE 1: concatenated [extra_feat(384), flow1(2), flow2(2)] input (Cin=388).
// EPI 0: plain store; EPI 1: leaky-relu(0.1); EPI 2: offset/mask transform
//        (oc<288: 10*tanh(v) + flow[b, 1-(oc&1)]; oc>=288: sigmoid).
template<int IN_MODE, int EPI>
__global__ __launch_bounds__(256) void conv3x3_k(
    const float* __restrict__ in, const float* __restrict__ aux1, const float* __restrict__ aux2,
    const float* __restrict__ w, const float* __restrict__ bias, float* __restrict__ out,
    int Cin, int Cout, const float* __restrict__ flow1, const float* __restrict__ flow2)
{
    __shared__ float tile[8][18][18];   // 8 input ch x (16+2)^2 halo tile
    const int t  = threadIdx.x;
    const int tx = t & 15, ty = t >> 4;
    const int x0 = blockIdx.x * 16, y0 = blockIdx.y * 16;
    const int nob = Cout >> 4;
    const int b   = blockIdx.z / nob;
    const int ocb = blockIdx.z % nob;

    float acc[16];
#pragma unroll
    for (int o = 0; o < 16; ++o) acc[o] = 0.f;

    const int nchunk = (Cin + 7) >> 3;
    for (int chk = 0; chk < nchunk; ++chk) {
        const int icb  = chk << 3;
        const int cend = min(8, Cin - icb);
        const int tot  = cend * 324;
        for (int idx = t; idx < tot; idx += 256) {
            int c   = idx / 324;
            int rem = idx - c * 324;
            int yy  = rem / 18, xx = rem - yy * 18;
            int gy  = y0 + yy - 1, gx = x0 + xx - 1;
            float v = 0.f;
            if (gy >= 0 && gy < HH && gx >= 0 && gx < WW) {
                int ic = icb + c;
                if (IN_MODE == 0) {
                    v = in[((size_t)(b * Cin + ic) * HH + gy) * WW + gx];
                } else {
                    if (ic < 384)      v = in  [((size_t)(b * 384 + ic)       * HH + gy) * WW + gx];
                    else if (ic < 386) v = aux1[((size_t)(b * 2 + (ic - 384)) * HH + gy) * WW + gx];
                    else               v = aux2[((size_t)(b * 2 + (ic - 386)) * HH + gy) * WW + gx];
                }
            }
            tile[c][yy][xx] = v;
        }
        __syncthreads();

        for (int c = 0; c < cend; ++c) {
            float iv[9];
#pragma unroll
            for (int j = 0; j < 9; ++j) iv[j] = tile[c][ty + j / 3][tx + (j % 3)];
            const int ic = icb + c;
#pragma unroll
            for (int o = 0; o < 16; ++o) {
                const float* wp = w + ((size_t)((ocb * 16 + o) * Cin) + ic) * 9;
#pragma unroll
                for (int j = 0; j < 9; ++j) acc[o] = fmaf(iv[j], wp[j], acc[o]);
            }
        }
        __syncthreads();
    }

    const int oy = y0 + ty, ox = x0 + tx;
#pragma unroll
    for (int o = 0; o < 16; ++o) {
        int oc = ocb * 16 + o;
        float v = acc[o] + bias[oc];
        if (EPI == 1) v = (v >= 0.f) ? v : 0.1f * v;
        if (EPI == 2) {
            if (oc < 288) {
                float tv = 10.f * tanhf(v);
                const float* fl = (oc < 144) ? flow1 : flow2;
                int fc = 1 - (oc & 1);
                tv += fl[((size_t)(b * 2 + fc) * HH + oy) * WW + ox];
                v = tv;
            } else {
                v = 1.f / (1.f + expf(-v));
            }
        }
        out[((size_t)(b * Cout + oc) * HH + oy) * WW + ox] = v;
    }
}

// Modulated deformable conv v2: x (B,128,H,W), h3 holds [offsets(288 ch, final
// dy/dx incl. flow), mask(144 ch, sigmoided)], weight (128,128,3,3), dg=16, cg=8.
// Block: 256 threads = 4 waves; 8x8 pixel tile; wave w computes oc [32w, 32w+32).
__global__ __launch_bounds__(256) void deform_k(
    const float* __restrict__ x, const float* __restrict__ h3,
    const float* __restrict__ w, const float* __restrict__ bias,
    float* __restrict__ out)
{
    __shared__ int   s_y0[64], s_x0[64];
    __shared__ float s_wy[64], s_wx[64], s_m[64];
    __shared__ float s_val[8][64];

    const int t    = threadIdx.x;
    const int p    = t & 63;
    const int wave = t >> 6;
    const int wb0  = blockIdx.x * 8, hb0 = blockIdx.y * 8;
    const int b    = blockIdx.z;
    const int ho   = hb0 + (p >> 3), wo = wb0 + (p & 7);

    float acc[32];
#pragma unroll
    for (int o = 0; o < 32; ++o) acc[o] = 0.f;

    for (int g = 0; g < 16; ++g) {
        for (int k = 0; k < 9; ++k) {
            if (t < 64) {
                int chb  = g * 18 + k * 2;
                float dy = h3[((size_t)(b * 432 + chb)             * HH + ho) * WW + wo];
                float dx = h3[((size_t)(b * 432 + chb + 1)         * HH + ho) * WW + wo];
                float m  = h3[((size_t)(b * 432 + 288 + g * 9 + k) * HH + ho) * WW + wo];
                float py = dy + (float)(ho + k / 3 - 1);
                float px = dx + (float)(wo + (k % 3) - 1);
                float fy = floorf(py), fx = floorf(px);
                s_y0[t] = (int)fy; s_x0[t] = (int)fx;
                s_wy[t] = py - fy; s_wx[t] = px - fx;
                s_m[t]  = m;
            }
            __syncthreads();

#pragma unroll
            for (int vv = 0; vv < 2; ++vv) {
                int v   = t + vv * 256;
                int c   = v >> 6, pix = v & 63;
                int yy0 = s_y0[pix], xx0 = s_x0[pix];
                float wy = s_wy[pix], wx = s_wx[pix];
                const float* xp = x + (size_t)(b * 128 + g * 8 + c) * HW;
                float v00 = 0.f, v01 = 0.f, v10 = 0.f, v11 = 0.f;
                if ((unsigned)yy0 < (unsigned)HH) {
                    if ((unsigned)xx0       < (unsigned)WW) v00 = xp[yy0 * WW + xx0];
                    if ((unsigned)(xx0 + 1) < (unsigned)WW) v01 = xp[yy0 * WW + xx0 + 1];
                }
                if ((unsigned)(yy0 + 1) < (unsigned)HH) {
                    if ((unsigned)xx0       < (unsigned)WW) v10 = xp[(yy0 + 1) * WW + xx0];
                    if ((unsigned)(xx0 + 1) < (unsigned)WW) v11 = xp[(yy0 + 1) * WW + xx0 + 1];
                }
                float bi = (1.f - wy) * ((1.f - wx) * v00 + wx * v01)
                         +        wy  * ((1.f - wx) * v10 + wx * v11);
                s_val[c][pix] = bi * s_m[pix];
            }
            __syncthreads();

            const int ic0 = g * 8;
#pragma unroll
            for (int c = 0; c < 8; ++c) {
                float v = s_val[c][p];
#pragma unroll
                for (int o = 0; o < 32; ++o) {
                    acc[o] = fmaf(v, w[((size_t)((wave * 32 + o) * 128) + ic0 + c) * 9 + k], acc[o]);
                }
            }
            __syncthreads();
        }
    }

#pragma unroll
    for (int o = 0; o < 32; ++o) {
        int oc = wave * 32 + o;
        out[((size_t)(b * 128 + oc) * HH + ho) * WW + wo] = acc[o] + bias[oc];
    }
}

extern "C" void kernel_launch(void* const* d_in, const int* in_sizes, int n_in,
                              void* d_out, int out_size, void* d_ws, size_t ws_size,
                              hipStream_t stream)
{
    const float* x    = (const float*)d_in[0];
    const float* ef   = (const float*)d_in[1];
    const float* f1   = (const float*)d_in[2];
    const float* f2   = (const float*)d_in[3];
    const float* wgt  = (const float*)d_in[4];
    const float* bias = (const float*)d_in[5];
    const float* cw0  = (const float*)d_in[6];
    const float* cb0  = (const float*)d_in[7];
    const float* cw1  = (const float*)d_in[8];
    const float* cb1  = (const float*)d_in[9];
    const float* cw2  = (const float*)d_in[10];
    const float* cb2  = (const float*)d_in[11];
    const float* cw3  = (const float*)d_in[12];
    const float* cb3  = (const float*)d_in[13];

    float* outp = (float*)d_out;
    // Scratch aliasing: h_a (15.7 MB, conv1->conv2 temp) is dead before h3
    // (53.1 MB, conv3 output) is first written -> both live at d_ws + 0.
    float* h_a  = (float*)d_ws;
    float* h3   = (float*)d_ws;

    dim3 blk(256);
    dim3 g8 (WW / 16, HH / 16, BB * 8);
    dim3 g27(WW / 16, HH / 16, BB * 27);
    dim3 gd (WW / 8,  HH / 8,  BB);

    // conv0: concat(ef, f1, f2) -> outp (lrelu)
    hipLaunchKernelGGL((conv3x3_k<1, 1>), g8, blk, 0, stream,
                       ef, f1, f2, cw0, cb0, outp, 388, 128, nullptr, nullptr);
    // conv1: outp -> h_a (lrelu)
    hipLaunchKernelGGL((conv3x3_k<0, 1>), g8, blk, 0, stream,
                       outp, nullptr, nullptr, cw1, cb1, h_a, 128, 128, nullptr, nullptr);
    // conv2: h_a -> outp (lrelu)
    hipLaunchKernelGGL((conv3x3_k<0, 1>), g8, blk, 0, stream,
                       h_a, nullptr, nullptr, cw2, cb2, outp, 128, 128, nullptr, nullptr);
    // conv3: outp -> h3 (offset/mask transform epilogue)
    hipLaunchKernelGGL((conv3x3_k<0, 2>), g27, blk, 0, stream,
                       outp, nullptr, nullptr, cw3, cb3, h3, 128, 432, f1, f2);
    // deform conv: x, h3 -> outp
    hipLaunchKernelGGL(deform_k, gd, blk, 0, stream, x, h3, wgt, bias, outp);
}

// Round 3
// 2552.240 us; speedup vs baseline: 1.4606x; 1.4606x over previous
//
#include <hip/hip_runtime.h>
#include <math.h>

#define BB 2
#define HH 96
#define WW 160
#define HW (HH*WW)

// Generic 3x3 conv, stride 1, pad 1.
// IN_MODE 0: plain NCHW input with Cin channels.
// IN_MODE 1: concatenated [extra_feat(384), flow1(2), flow2(2)] input (Cin=388).
// EPI 0: plain store; EPI 1: leaky-relu(0.1); EPI 2: offset/mask transform
//        (oc<288: 10*tanh(v) + flow[b, 1-(oc&1)]; oc>=288: sigmoid).
template<int IN_MODE, int EPI>
__global__ __launch_bounds__(256) void conv3x3_k(
    const float* __restrict__ in, const float* __restrict__ aux1, const float* __restrict__ aux2,
    const float* __restrict__ w, const float* __restrict__ bias, float* __restrict__ out,
    int Cin, int Cout, const float* __restrict__ flow1, const float* __restrict__ flow2)
{
    __shared__ float tile[8][18][18];   // 8 input ch x (16+2)^2 halo tile
    const int t  = threadIdx.x;
    const int tx = t & 15, ty = t >> 4;
    const int x0 = blockIdx.x * 16, y0 = blockIdx.y * 16;
    const int nob = Cout >> 4;
    const int b   = blockIdx.z / nob;
    const int ocb = blockIdx.z % nob;

    float acc[16];
#pragma unroll
    for (int o = 0; o < 16; ++o) acc[o] = 0.f;

    const int nchunk = (Cin + 7) >> 3;
    for (int chk = 0; chk < nchunk; ++chk) {
        const int icb  = chk << 3;
        const int cend = min(8, Cin - icb);
        const int tot  = cend * 324;
        for (int idx = t; idx < tot; idx += 256) {
            int c   = idx / 324;
            int rem = idx - c * 324;
            int yy  = rem / 18, xx = rem - yy * 18;
            int gy  = y0 + yy - 1, gx = x0 + xx - 1;
            float v = 0.f;
            if (gy >= 0 && gy < HH && gx >= 0 && gx < WW) {
                int ic = icb + c;
                if (IN_MODE == 0) {
                    v = in[((size_t)(b * Cin + ic) * HH + gy) * WW + gx];
                } else {
                    if (ic < 384)      v = in  [((size_t)(b * 384 + ic)       * HH + gy) * WW + gx];
                    else if (ic < 386) v = aux1[((size_t)(b * 2 + (ic - 384)) * HH + gy) * WW + gx];
                    else               v = aux2[((size_t)(b * 2 + (ic - 386)) * HH + gy) * WW + gx];
                }
            }
            tile[c][yy][xx] = v;
        }
        __syncthreads();

        for (int c = 0; c < cend; ++c) {
            float iv[9];
#pragma unroll
            for (int j = 0; j < 9; ++j) iv[j] = tile[c][ty + j / 3][tx + (j % 3)];
            const int ic = icb + c;
#pragma unroll
            for (int o = 0; o < 16; ++o) {
                const float* wp = w + ((size_t)((ocb * 16 + o) * Cin) + ic) * 9;
#pragma unroll
                for (int j = 0; j < 9; ++j) acc[o] = fmaf(iv[j], wp[j], acc[o]);
            }
        }
        __syncthreads();
    }

    const int oy = y0 + ty, ox = x0 + tx;
#pragma unroll
    for (int o = 0; o < 16; ++o) {
        int oc = ocb * 16 + o;
        float v = acc[o] + bias[oc];
        if (EPI == 1) v = (v >= 0.f) ? v : 0.1f * v;
        if (EPI == 2) {
            if (oc < 288) {
                float tv = 10.f * tanhf(v);
                const float* fl = (oc < 144) ? flow1 : flow2;
                int fc = 1 - (oc & 1);
                tv += fl[((size_t)(b * 2 + fc) * HH + oy) * WW + ox];
                v = tv;
            } else {
                v = 1.f / (1.f + expf(-v));
            }
        }
        out[((size_t)(b * Cout + oc) * HH + oy) * WW + ox] = v;
    }
}

// Weight transpose: wT[(pair*8 + c)*128 + oc] = w[oc][g*8+c][k], pair = g*9+k.
// Gives the deform FMA loop contiguous per-(pair,c) runs of 128 oc for s_load.
__global__ __launch_bounds__(256) void wtrans_k(const float* __restrict__ w, float* __restrict__ wT)
{
    int tid = blockIdx.x * 256 + threadIdx.x;
    if (tid < 128 * 128 * 9) {
        int oc   = tid & 127;
        int pc   = tid >> 7;          // 0..1151 = pair*8 + c
        int c    = pc & 7;
        int pair = pc >> 3;
        int g    = pair / 9, k = pair - g * 9;
        wT[tid] = w[((size_t)(oc * 128) + g * 8 + c) * 9 + k];
    }
}

// out[b][oc][hw] = bias[oc]  (deform blocks then atomicAdd their partial sums)
__global__ __launch_bounds__(256) void init_out_k(const float* __restrict__ bias, float* __restrict__ out)
{
    int idx = blockIdx.x * 256 + threadIdx.x;
    if (idx < BB * 128 * HW) {
        int oc = (idx / HW) & 127;
        out[idx] = bias[oc];
    }
}

// Modulated deformable conv v2, restructured:
// - block = 256 threads (4 waves), 8x8 pixel tile, 4 of the 16 deform-groups
//   (blockIdx.z = b*4 + gs) -> 1920 blocks.
// - 9 chunks of 4 (g,k) tap-pairs; per chunk: parallel offset calc (256 thr),
//   barrier, gather 2048 samples (8/thr), barrier, FMA with SGPR weights.
// - wave wv owns oc [32*wv, 32*wv+32); partials atomicAdd'ed into out.
__global__ __launch_bounds__(256) void deform2_k(
    const float* __restrict__ x, const float* __restrict__ h3,
    const float* __restrict__ wT, float* __restrict__ out)
{
    __shared__ int   s_y0[4][64], s_x0[4][64];
    __shared__ float s_wy[4][64], s_wx[4][64], s_m[4][64];
    __shared__ float s_val[4][8][64];

    const int t   = threadIdx.x;
    const int p   = t & 63;
    const int wv  = __builtin_amdgcn_readfirstlane(t >> 6);
    const int wb0 = blockIdx.x * 8, hb0 = blockIdx.y * 8;
    const int b   = blockIdx.z >> 2;
    const int gs  = blockIdx.z & 3;
    const int ho  = hb0 + (p >> 3), wo = wb0 + (p & 7);

    float acc[32];
#pragma unroll
    for (int o = 0; o < 32; ++o) acc[o] = 0.f;

    const int pairbase = gs * 36;
    const float* hb = h3 + (size_t)b * 432 * HW + ho * WW + wo;

    for (int ch = 0; ch < 9; ++ch) {
        const int pb = pairbase + ch * 4;

        // Phase A: thread (wv, p) computes offset/mask for pair pb+wv, pixel p.
        {
            int pair = pb + wv;
            int g = pair / 9, k = pair - (pair / 9) * 9;
            float dy = hb[(size_t)(g * 18 + k * 2)     * HW];
            float dx = hb[(size_t)(g * 18 + k * 2 + 1) * HW];
            float m  = hb[(size_t)(288 + g * 9 + k)    * HW];
            float py = dy + (float)(ho + k / 3 - 1);
            float px = dx + (float)(wo + (k % 3) - 1);
            float fy = floorf(py), fx = floorf(px);
            s_y0[wv][p] = (int)fy; s_x0[wv][p] = (int)fx;
            s_wy[wv][p] = py - fy; s_wx[wv][p] = px - fx;
            s_m[wv][p]  = m;
        }
        __syncthreads();   // off ready; prev-chunk s_val reads all done

        // Phase B: gather+bilinear: 4 pairs x 8 ch x 64 pix = 2048 samples.
        #pragma unroll
        for (int i = 0; i < 8; ++i) {
            int m4 = i * 4 + wv;            // 0..31, bijective -> (j, c)
            int j  = m4 >> 3, c = m4 & 7;
            int pair = pb + j;
            int g  = pair / 9;
            const float* xp = x + ((size_t)(b * 128) + g * 8 + c) * HW;
            int   yy0 = s_y0[j][p], xx0 = s_x0[j][p];
            float wy  = s_wy[j][p], wx  = s_wx[j][p];
            float v00 = 0.f, v01 = 0.f, v10 = 0.f, v11 = 0.f;
            bool x0ok = (unsigned)xx0       < (unsigned)WW;
            bool x1ok = (unsigned)(xx0 + 1) < (unsigned)WW;
            if ((unsigned)yy0 < (unsigned)HH) {
                const float* r = xp + yy0 * WW;
                if (x0ok) v00 = r[xx0];
                if (x1ok) v01 = r[xx0 + 1];
            }
            if ((unsigned)(yy0 + 1) < (unsigned)HH) {
                const float* r = xp + (yy0 + 1) * WW;
                if (x0ok) v10 = r[xx0];
                if (x1ok) v11 = r[xx0 + 1];
            }
            float bi = (1.f - wy) * ((1.f - wx) * v00 + wx * v01)
                     +        wy  * ((1.f - wx) * v10 + wx * v11);
            s_val[j][c][p] = bi * s_m[j][p];
        }
        __syncthreads();   // val ready; off free for next chunk

        // Phase C: FMA. Weights via wave-uniform (SGPR) addresses.
        const float* wtb = wT + (size_t)pb * 8 * 128 + wv * 32;
        #pragma unroll
        for (int j = 0; j < 4; ++j) {
            #pragma unroll
            for (int c = 0; c < 8; ++c) {
                float v = s_val[j][c][p];
                const float* wp = wtb + (j * 8 + c) * 128;
                #pragma unroll
                for (int o = 0; o < 32; ++o)
                    acc[o] = fmaf(v, wp[o], acc[o]);
            }
        }
    }

    float* op = out + ((size_t)(b * 128) + wv * 32) * HW + ho * WW + wo;
#pragma unroll
    for (int o = 0; o < 32; ++o)
        atomicAdd(op + (size_t)o * HW, acc[o]);
}

extern "C" void kernel_launch(void* const* d_in, const int* in_sizes, int n_in,
                              void* d_out, int out_size, void* d_ws, size_t ws_size,
                              hipStream_t stream)
{
    const float* x    = (const float*)d_in[0];
    const float* ef   = (const float*)d_in[1];
    const float* f1   = (const float*)d_in[2];
    const float* f2   = (const float*)d_in[3];
    const float* wgt  = (const float*)d_in[4];
    const float* bias = (const float*)d_in[5];
    const float* cw0  = (const float*)d_in[6];
    const float* cb0  = (const float*)d_in[7];
    const float* cw1  = (const float*)d_in[8];
    const float* cb1  = (const float*)d_in[9];
    const float* cw2  = (const float*)d_in[10];
    const float* cb2  = (const float*)d_in[11];
    const float* cw3  = (const float*)d_in[12];
    const float* cb3  = (const float*)d_in[13];

    float* outp = (float*)d_out;
    // ws layout: wT at [0, 576KB); h_a/h3 aliased at [16MB, 69.1MB)
    // (h_a dead before h3's first write).
    float* wT   = (float*)d_ws;
    float* h_a  = (float*)((char*)d_ws + (size_t)16 * 1024 * 1024);
    float* h3   = h_a;

    dim3 blk(256);
    dim3 g8 (WW / 16, HH / 16, BB * 8);
    dim3 g27(WW / 16, HH / 16, BB * 27);
    dim3 gd (WW / 8,  HH / 8,  BB * 4);

    hipLaunchKernelGGL(wtrans_k, dim3((128 * 128 * 9 + 255) / 256), blk, 0, stream, wgt, wT);
    // conv0: concat(ef, f1, f2) -> outp (lrelu)
    hipLaunchKernelGGL((conv3x3_k<1, 1>), g8, blk, 0, stream,
                       ef, f1, f2, cw0, cb0, outp, 388, 128, nullptr, nullptr);
    // conv1: outp -> h_a (lrelu)
    hipLaunchKernelGGL((conv3x3_k<0, 1>), g8, blk, 0, stream,
                       outp, nullptr, nullptr, cw1, cb1, h_a, 128, 128, nullptr, nullptr);
    // conv2: h_a -> outp (lrelu)
    hipLaunchKernelGGL((conv3x3_k<0, 1>), g8, blk, 0, stream,
                       h_a, nullptr, nullptr, cw2, cb2, outp, 128, 128, nullptr, nullptr);
    // conv3: outp -> h3 (offset/mask transform epilogue)
    hipLaunchKernelGGL((conv3x3_k<0, 2>), g27, blk, 0, stream,
                       outp, nullptr, nullptr, cw3, cb3, h3, 128, 432, f1, f2);
    // out = bias, then deform partials atomicAdd into it
    hipLaunchKernelGGL(init_out_k, dim3((BB * 128 * HW + 255) / 256), blk, 0, stream, bias, outp);
    hipLaunchKernelGGL(deform2_k, gd, blk, 0, stream, x, h3, wT, outp);
}

// Round 4
// 1050.643 us; speedup vs baseline: 3.5481x; 2.4292x over previous
//
#include <hip/hip_runtime.h>
#include <hip/hip_fp16.h>
#include <math.h>

#define BB 2
#define HH 96
#define WW 160
#define HW (HH*WW)

typedef short bf16x8 __attribute__((ext_vector_type(8)));
typedef float f32x4  __attribute__((ext_vector_type(4)));

__device__ inline unsigned short f2bf(float v) {
    unsigned u = __float_as_uint(v);
    unsigned r = (u + 0x7FFF + ((u >> 16) & 1)) >> 16;   // RNE
    return (unsigned short)r;
}
__device__ inline float bf2f(unsigned short s) {
    return __uint_as_float(((unsigned)s) << 16);
}

// Split fp32 conv weights into hi/lo bf16, layout [tap][ocP][icP] (zero-padded).
__global__ __launch_bounds__(256) void wsplit_k(
    const float* __restrict__ src, int Cout, int Cin, int OCP, int ICP,
    unsigned short* __restrict__ dh, unsigned short* __restrict__ dl)
{
    int idx = blockIdx.x * 256 + threadIdx.x;
    if (idx >= 9 * OCP * ICP) return;
    int ic  = idx % ICP;
    int q   = idx / ICP;
    int oc  = q % OCP;
    int tap = q / OCP;
    float v = (oc < Cout && ic < Cin) ? src[((size_t)oc * Cin + ic) * 9 + tap] : 0.f;
    unsigned short hs = f2bf(v);
    dh[idx] = hs;
    dl[idx] = f2bf(v - bf2f(hs));
}

// ===========================================================================
// Split-bf16 MFMA 3x3 conv.  BM=128 oc, BN = 2 rows x 32 cols, BK=32.
// 4 waves: (wm = wave>>1) picks oc-half, (wn = wave&1) picks output row.
// Each wave: 4 m-frags x 2 n-frags; per tap: 8 A global loads, 4 swizzled
// ds_read_b128 B-frags, 12 MFMA (hh + hl + lh).
// IN_MODE 1: stage from concat fp32 [ef(384)|f1(2)|f2(2)], split on the fly.
// IN_MODE 0: stage from bf16 NHWC hi/lo planes written by previous conv.
// EPI 1: +bias, lrelu, write NHWC hi/lo bf16.  EPI 2: +bias, offset/mask
// transform, write fp16 NCHW h3 (oc<432 only).
// ===========================================================================
template<int IN_MODE, int EPI, int NCHUNK, int ICP, int OCP>
__global__ __launch_bounds__(256) void conv_mfma(
    const float* __restrict__ ef, const float* __restrict__ f1, const float* __restrict__ f2,
    const unsigned short* __restrict__ inH, const unsigned short* __restrict__ inL,
    const unsigned short* __restrict__ Wh, const unsigned short* __restrict__ Wl,
    const float* __restrict__ bias,
    unsigned short* __restrict__ outH, unsigned short* __restrict__ outL,
    __half* __restrict__ h3)
{
    __shared__ int4 bsmem[1280];                 // 20480 B: [pl2][row4][col40][ic32] bf16, swizzled
    char* lds_c = (char*)bsmem;

    const int t  = threadIdx.x;
    const int l  = t & 63;
    const int lr = l >> 4;                       // 0..3
    const int lc = l & 15;
    const int wv = __builtin_amdgcn_readfirstlane(t >> 6);
    const int wm = wv >> 1, wn = wv & 1;

    const int colseg  = blockIdx.x;              // 0..4 (32 cols each)
    const int rowpair = blockIdx.y;              // 0..47 (2 rows each)
    const int MB      = OCP / 128;
    const int b       = blockIdx.z / MB;
    const int mblk    = blockIdx.z % MB;

    f32x4 acc[4][2];
#pragma unroll
    for (int m = 0; m < 4; ++m)
#pragma unroll
        for (int n = 0; n < 2; ++n)
#pragma unroll
            for (int j = 0; j < 4; ++j) acc[m][n][j] = 0.f;

    const int pixbase = b * HW;

    for (int chunk = 0; chunk < NCHUNK; ++chunk) {
        const int kbase = chunk * 32;

        // ---- stage B tile: rows rowpair*2-1 .. +2, cols colseg*32-1 .. +32 ----
        if (IN_MODE == 0) {
            for (int s = t; s < 1088; s += 256) {
                int icg = s & 3;
                int q   = s >> 2;
                int col = q % 34;
                int r   = q / 34;                // pl*4 + row
                int row = r & 3;
                int pl  = r >> 2;
                int gh = rowpair * 2 + row - 1;
                int gw = colseg * 32 + col - 1;
                bf16x8 v;
#pragma unroll
                for (int i = 0; i < 8; ++i) v[i] = 0;
                if ((unsigned)gh < (unsigned)HH && (unsigned)gw < (unsigned)WW) {
                    const unsigned short* src = pl ? inL : inH;
                    v = *(const bf16x8*)(src + ((size_t)(pixbase + gh * WW + gw) * 128 + kbase + icg * 8));
                }
                int byte = ((r * 40 + col) << 6) + (icg << 4);
                byte ^= (col & 7) << 4;
                *(bf16x8*)(lds_c + byte) = v;
            }
        } else {
            for (int s = t; s < 4352; s += 256) {
                int col = s % 34;
                int q   = s / 34;
                int row = q & 3;
                int ic  = q >> 2;
                int c   = kbase + ic;
                int gh = rowpair * 2 + row - 1;
                int gw = colseg * 32 + col - 1;
                float v = 0.f;
                if ((unsigned)gh < (unsigned)HH && (unsigned)gw < (unsigned)WW) {
                    int pix = gh * WW + gw;
                    if (c < 384)      v = ef[((size_t)(b * 384 + c)) * HW + pix];
                    else if (c < 386) v = f1[((size_t)(b * 2 + c - 384)) * HW + pix];
                    else if (c < 388) v = f2[((size_t)(b * 2 + c - 386)) * HW + pix];
                }
                unsigned short hs = f2bf(v);
                unsigned short ls = f2bf(v - bf2f(hs));
                int ebyte = (row * 40 + col) * 64 + ic * 2;
                int sw = (col & 7) << 4;
                *(unsigned short*)(lds_c + (ebyte ^ sw))           = hs;
                *(unsigned short*)(lds_c + ((ebyte ^ sw) + 10240)) = ls;
            }
        }
        __syncthreads();

        // ---- 9 taps: A from global (hot in cache), B from LDS, 12 MFMA each ----
#pragma unroll
        for (int ky = 0; ky < 3; ++ky) {
#pragma unroll
            for (int kx = 0; kx < 3; ++kx) {
                const int tap = ky * 3 + kx;
                const size_t wbase = ((size_t)tap * OCP + mblk * 128 + wm * 64 + lc) * ICP + kbase + lr * 8;
                bf16x8 Ah[4], Al[4];
#pragma unroll
                for (int mf = 0; mf < 4; ++mf) {
                    Ah[mf] = *(const bf16x8*)(Wh + wbase + (size_t)mf * 16 * ICP);
                    Al[mf] = *(const bf16x8*)(Wl + wbase + (size_t)mf * 16 * ICP);
                }
                const int rowi = ky + wn;        // 0..3
                bf16x8 Bh[2], Bl[2];
#pragma unroll
                for (int nfl = 0; nfl < 2; ++nfl) {
                    int col  = kx + nfl * 16 + lc;
                    int byte = ((rowi * 40 + col) << 6) + (lr << 4);
                    byte ^= (col & 7) << 4;
                    Bh[nfl] = *(const bf16x8*)(lds_c + byte);
                    Bl[nfl] = *(const bf16x8*)(lds_c + byte + 10240);
                }
#pragma unroll
                for (int mf = 0; mf < 4; ++mf) {
#pragma unroll
                    for (int nfl = 0; nfl < 2; ++nfl) {
                        acc[mf][nfl] = __builtin_amdgcn_mfma_f32_16x16x32_bf16(Al[mf], Bh[nfl], acc[mf][nfl], 0, 0, 0);
                        acc[mf][nfl] = __builtin_amdgcn_mfma_f32_16x16x32_bf16(Ah[mf], Bl[nfl], acc[mf][nfl], 0, 0, 0);
                        acc[mf][nfl] = __builtin_amdgcn_mfma_f32_16x16x32_bf16(Ah[mf], Bh[nfl], acc[mf][nfl], 0, 0, 0);
                    }
                }
            }
        }
        __syncthreads();
    }

    // ---- epilogue ----
    const int h = rowpair * 2 + wn;
#pragma unroll
    for (int mf = 0; mf < 4; ++mf) {
        const int ocb = (wm * 4 + mf) * 16 + lr * 4;     // local oc base (0..127)
#pragma unroll
        for (int nfl = 0; nfl < 2; ++nfl) {
            const int w = colseg * 32 + nfl * 16 + lc;
#pragma unroll
            for (int j = 0; j < 4; ++j) {
                float v = acc[mf][nfl][j];
                if (EPI == 1) {
                    int oc = ocb + j;                    // mblk==0
                    v += bias[oc];
                    v = (v >= 0.f) ? v : 0.1f * v;
                    size_t idx = (size_t)(pixbase + h * WW + w) * 128 + oc;
                    unsigned short hs = f2bf(v);
                    outH[idx] = hs;
                    outL[idx] = f2bf(v - bf2f(hs));
                } else {
                    int oc = mblk * 128 + ocb + j;
                    if (oc < 432) {
                        v += bias[oc];
                        size_t idx = ((size_t)(b * 432 + oc)) * HW + h * WW + w;
                        if (oc < 288) {
                            float e  = __expf(2.f * v);
                            float th = 1.f - 2.f / (e + 1.f);
                            float off = 10.f * th;
                            const float* fl = (oc < 144) ? f1 : f2;
                            off += fl[((size_t)(b * 2 + (1 - (oc & 1)))) * HW + h * WW + w];
                            h3[idx] = __float2half(off);
                        } else {
                            h3[idx] = __float2half(1.f / (1.f + __expf(-v)));
                        }
                    }
                }
            }
        }
    }
}

// Weight transpose for deform: wT[(pair*8 + c)*128 + oc] = w[oc][g*8+c][k].
__global__ __launch_bounds__(256) void wtrans_k(const float* __restrict__ w, float* __restrict__ wT)
{
    int tid = blockIdx.x * 256 + threadIdx.x;
    if (tid < 128 * 128 * 9) {
        int oc   = tid & 127;
        int pc   = tid >> 7;
        int c    = pc & 7;
        int pair = pc >> 3;
        int g    = pair / 9, k = pair - g * 9;
        wT[tid] = w[((size_t)(oc * 128) + g * 8 + c) * 9 + k];
    }
}

__global__ __launch_bounds__(256) void init_out_k(const float* __restrict__ bias, float* __restrict__ out)
{
    int idx = blockIdx.x * 256 + threadIdx.x;
    if (idx < BB * 128 * HW) {
        int oc = (idx / HW) & 127;
        out[idx] = bias[oc];
    }
}

// Modulated deformable conv v2 (h3 now fp16).
__global__ __launch_bounds__(256) void deform2_k(
    const float* __restrict__ x, const __half* __restrict__ h3,
    const float* __restrict__ wT, float* __restrict__ out)
{
    __shared__ int   s_y0[4][64], s_x0[4][64];
    __shared__ float s_wy[4][64], s_wx[4][64], s_m[4][64];
    __shared__ float s_val[4][8][64];

    const int t   = threadIdx.x;
    const int p   = t & 63;
    const int wv  = __builtin_amdgcn_readfirstlane(t >> 6);
    const int wb0 = blockIdx.x * 8, hb0 = blockIdx.y * 8;
    const int b   = blockIdx.z >> 2;
    const int gs  = blockIdx.z & 3;
    const int ho  = hb0 + (p >> 3), wo = wb0 + (p & 7);

    float acc[32];
#pragma unroll
    for (int o = 0; o < 32; ++o) acc[o] = 0.f;

    const int pairbase = gs * 36;
    const __half* hb = h3 + (size_t)b * 432 * HW + ho * WW + wo;

    for (int ch = 0; ch < 9; ++ch) {
        const int pb = pairbase + ch * 4;

        {
            int pair = pb + wv;
            int g = pair / 9, k = pair - (pair / 9) * 9;
            float dy = __half2float(hb[(size_t)(g * 18 + k * 2)     * HW]);
            float dx = __half2float(hb[(size_t)(g * 18 + k * 2 + 1) * HW]);
            float m  = __half2float(hb[(size_t)(288 + g * 9 + k)    * HW]);
            float py = dy + (float)(ho + k / 3 - 1);
            float px = dx + (float)(wo + (k % 3) - 1);
            float fy = floorf(py), fx = floorf(px);
            s_y0[wv][p] = (int)fy; s_x0[wv][p] = (int)fx;
            s_wy[wv][p] = py - fy; s_wx[wv][p] = px - fx;
            s_m[wv][p]  = m;
        }
        __syncthreads();

        #pragma unroll
        for (int i = 0; i < 8; ++i) {
            int m4 = i * 4 + wv;
            int j  = m4 >> 3, c = m4 & 7;
            int pair = pb + j;
            int g  = pair / 9;
            const float* xp = x + ((size_t)(b * 128) + g * 8 + c) * HW;
            int   yy0 = s_y0[j][p], xx0 = s_x0[j][p];
            float wy  = s_wy[j][p], wx  = s_wx[j][p];
            float v00 = 0.f, v01 = 0.f, v10 = 0.f, v11 = 0.f;
            bool x0ok = (unsigned)xx0       < (unsigned)WW;
            bool x1ok = (unsigned)(xx0 + 1) < (unsigned)WW;
            if ((unsigned)yy0 < (unsigned)HH) {
                const float* r = xp + yy0 * WW;
                if (x0ok) v00 = r[xx0];
                if (x1ok) v01 = r[xx0 + 1];
            }
            if ((unsigned)(yy0 + 1) < (unsigned)HH) {
                const float* r = xp + (yy0 + 1) * WW;
                if (x0ok) v10 = r[xx0];
                if (x1ok) v11 = r[xx0 + 1];
            }
            float bi = (1.f - wy) * ((1.f - wx) * v00 + wx * v01)
                     +        wy  * ((1.f - wx) * v10 + wx * v11);
            s_val[j][c][p] = bi * s_m[j][p];
        }
        __syncthreads();

        const float* wtb = wT + (size_t)pb * 8 * 128 + wv * 32;
        #pragma unroll
        for (int j = 0; j < 4; ++j) {
            #pragma unroll
            for (int c = 0; c < 8; ++c) {
                float v = s_val[j][c][p];
                const float* wp = wtb + (j * 8 + c) * 128;
                #pragma unroll
                for (int o = 0; o < 32; ++o)
                    acc[o] = fmaf(v, wp[o], acc[o]);
            }
        }
    }

    float* op = out + ((size_t)(b * 128) + wv * 32) * HW + ho * WW + wo;
#pragma unroll
    for (int o = 0; o < 32; ++o)
        atomicAdd(op + (size_t)o * HW, acc[o]);
}

extern "C" void kernel_launch(void* const* d_in, const int* in_sizes, int n_in,
                              void* d_out, int out_size, void* d_ws, size_t ws_size,
                              hipStream_t stream)
{
    const float* x    = (const float*)d_in[0];
    const float* ef   = (const float*)d_in[1];
    const float* f1   = (const float*)d_in[2];
    const float* f2   = (const float*)d_in[3];
    const float* wgt  = (const float*)d_in[4];
    const float* bias = (const float*)d_in[5];
    const float* cw0  = (const float*)d_in[6];
    const float* cb0  = (const float*)d_in[7];
    const float* cw1  = (const float*)d_in[8];
    const float* cb1  = (const float*)d_in[9];
    const float* cw2  = (const float*)d_in[10];
    const float* cb2  = (const float*)d_in[11];
    const float* cw3  = (const float*)d_in[12];
    const float* cb3  = (const float*)d_in[13];

    float* outp = (float*)d_out;
    char*  ws   = (char*)d_ws;

    // ---- ws layout (bytes) ----
    float*          wT   = (float*)         (ws + 0);           // 589,824
    unsigned short* W0h  = (unsigned short*)(ws + 589824);      // 958,464
    unsigned short* W0l  = (unsigned short*)(ws + 1548288);
    unsigned short* W1h  = (unsigned short*)(ws + 2506752);     // 294,912
    unsigned short* W1l  = (unsigned short*)(ws + 2801664);
    unsigned short* W2h  = (unsigned short*)(ws + 3096576);
    unsigned short* W2l  = (unsigned short*)(ws + 3391488);
    unsigned short* W3h  = (unsigned short*)(ws + 3686400);     // 1,179,648
    unsigned short* W3l  = (unsigned short*)(ws + 4866048);
    unsigned short* o0H  = (unsigned short*)(ws + 6045696);     // 7,864,320 each
    unsigned short* o0L  = (unsigned short*)(ws + 13910016);
    unsigned short* o1H  = (unsigned short*)(ws + 21774336);
    unsigned short* o1L  = (unsigned short*)(ws + 29638656);
    unsigned short* o2H  = (unsigned short*)(ws + 37502976);
    unsigned short* o2L  = (unsigned short*)(ws + 45367296);
    // h3 (fp16, 26,542,080 B) overlays dead out0/out1 region
    __half*         h3   = (__half*)        (ws + 6045696);

    dim3 blk(256);

    // weight prep
    hipLaunchKernelGGL(wtrans_k, dim3((128 * 128 * 9 + 255) / 256), blk, 0, stream, wgt, wT);
    hipLaunchKernelGGL(wsplit_k, dim3((9 * 128 * 416 + 255) / 256), blk, 0, stream, cw0, 128, 388, 128, 416, W0h, W0l);
    hipLaunchKernelGGL(wsplit_k, dim3((9 * 128 * 128 + 255) / 256), blk, 0, stream, cw1, 128, 128, 128, 128, W1h, W1l);
    hipLaunchKernelGGL(wsplit_k, dim3((9 * 128 * 128 + 255) / 256), blk, 0, stream, cw2, 128, 128, 128, 128, W2h, W2l);
    hipLaunchKernelGGL(wsplit_k, dim3((9 * 512 * 128 + 255) / 256), blk, 0, stream, cw3, 432, 128, 512, 128, W3h, W3l);

    dim3 gc(5, 48, BB);          // conv0/1/2
    dim3 gc3(5, 48, BB * 4);     // conv3 (OCP=512 -> 4 m-blocks)

    // conv0: concat fp32 -> o0 (lrelu, NHWC hi/lo)
    hipLaunchKernelGGL((conv_mfma<1, 1, 13, 416, 128>), gc, blk, 0, stream,
                       ef, f1, f2, nullptr, nullptr, W0h, W0l, cb0, o0H, o0L, nullptr);
    // conv1: o0 -> o1
    hipLaunchKernelGGL((conv_mfma<0, 1, 4, 128, 128>), gc, blk, 0, stream,
                       nullptr, nullptr, nullptr, o0H, o0L, W1h, W1l, cb1, o1H, o1L, nullptr);
    // conv2: o1 -> o2
    hipLaunchKernelGGL((conv_mfma<0, 1, 4, 128, 128>), gc, blk, 0, stream,
                       nullptr, nullptr, nullptr, o1H, o1L, W2h, W2l, cb2, o2H, o2L, nullptr);
    // conv3: o2 -> h3 (fp16, offset/mask epilogue)  [h3 overlays dead o0/o1]
    hipLaunchKernelGGL((conv_mfma<0, 2, 4, 128, 512>), gc3, blk, 0, stream,
                       nullptr, f1, f2, o2H, o2L, W3h, W3l, cb3, nullptr, nullptr, h3);

    // out = bias; deform partials atomicAdd into it
    hipLaunchKernelGGL(init_out_k, dim3((BB * 128 * HW + 255) / 256), blk, 0, stream, bias, outp);
    hipLaunchKernelGGL(deform2_k, dim3(WW / 8, HH / 8, BB * 4), blk, 0, stream, x, h3, wT, outp);
}

// Round 5
// 873.012 us; speedup vs baseline: 4.2700x; 1.2035x over previous
//
#include <hip/hip_runtime.h>
#include <hip/hip_fp16.h>
#include <math.h>

#define BB 2
#define HH 96
#define WW 160
#define HW (HH*WW)

typedef short bf16x8 __attribute__((ext_vector_type(8)));
typedef float f32x4  __attribute__((ext_vector_type(4)));

__device__ inline unsigned short f2bf(float v) {
    unsigned u = __float_as_uint(v);
    unsigned r = (u + 0x7FFF + ((u >> 16) & 1)) >> 16;   // RNE
    return (unsigned short)r;
}
__device__ inline float bf2f(unsigned short s) {
    return __uint_as_float(((unsigned)s) << 16);
}

// Split fp32 conv weights into hi/lo bf16, layout [tap][ocP][icP] (zero-padded).
__global__ __launch_bounds__(256) void wsplit_k(
    const float* __restrict__ src, int Cout, int Cin, int OCP, int ICP,
    unsigned short* __restrict__ dh, unsigned short* __restrict__ dl)
{
    int idx = blockIdx.x * 256 + threadIdx.x;
    if (idx >= 9 * OCP * ICP) return;
    int ic  = idx % ICP;
    int q   = idx / ICP;
    int oc  = q % OCP;
    int tap = q / OCP;
    float v = (oc < Cout && ic < Cin) ? src[((size_t)oc * Cin + ic) * 9 + tap] : 0.f;
    unsigned short hs = f2bf(v);
    dh[idx] = hs;
    dl[idx] = f2bf(v - bf2f(hs));
}

// ===========================================================================
// Split-bf16 MFMA 3x3 conv.  BM=128 oc, BN = 4 rows x 32 cols = 128 px, BK=32.
// 4 waves: wm = oc-half (64 oc, 4 m-frags), wn = row-pair (2 rows x 32 cols =
// 4 n-frags).  Per tap: 8 A-loads (double-buffered across taps), 8 swizzled
// ds_read_b128 B-frags, 48 MFMA (hh + hl + lh split product).
// IN_MODE 1: stage from concat fp32 [ef(384)|f1(2)|f2(2)], split on the fly.
// IN_MODE 0: stage from bf16 NHWC hi/lo planes written by previous conv.
// EPI 1: +bias, lrelu, write NHWC hi/lo bf16.  EPI 2: +bias, offset/mask
// transform, write fp16 NCHW h3 (oc<432 only).
// ===========================================================================
#define LOADA(DH, DL, TAP) {                                                          \
    const size_t wb_ = ((size_t)((TAP) * OCP + mblk * 128 + wm * 64 + lc)) * ICP      \
                       + kbase + lr * 8;                                              \
    _Pragma("unroll")                                                                 \
    for (int mf_ = 0; mf_ < 4; ++mf_) {                                               \
        DH[mf_] = *(const bf16x8*)(Wh + wb_ + (size_t)mf_ * 16 * ICP);                \
        DL[mf_] = *(const bf16x8*)(Wl + wb_ + (size_t)mf_ * 16 * ICP);                \
    } }

template<int IN_MODE, int EPI, int NCHUNK, int ICP, int OCP>
__global__ __launch_bounds__(256, 2) void conv_mfma(
    const float* __restrict__ ef, const float* __restrict__ f1, const float* __restrict__ f2,
    const unsigned short* __restrict__ inH, const unsigned short* __restrict__ inL,
    const unsigned short* __restrict__ Wh, const unsigned short* __restrict__ Wl,
    const float* __restrict__ bias,
    unsigned short* __restrict__ outH, unsigned short* __restrict__ outL,
    __half* __restrict__ h3)
{
    __shared__ char lds_c[30720];            // [pl2][row6][col40][ic32] bf16, swizzled

    const int t  = threadIdx.x;
    const int l  = t & 63;
    const int lr = l >> 4;                   // 0..3 (k-quarter)
    const int lc = l & 15;                   // 0..15
    const int wv = __builtin_amdgcn_readfirstlane(t >> 6);
    const int wm = wv >> 1, wn = wv & 1;

    const int colseg  = blockIdx.x;          // 0..4  (32 cols)
    const int rowquad = blockIdx.y;          // 0..23 (4 rows)
    const int MB      = OCP / 128;
    const int b       = blockIdx.z / MB;
    const int mblk    = blockIdx.z % MB;

    f32x4 acc[4][4];
#pragma unroll
    for (int m = 0; m < 4; ++m)
#pragma unroll
        for (int n = 0; n < 4; ++n)
#pragma unroll
            for (int j = 0; j < 4; ++j) acc[m][n][j] = 0.f;

    const int pixbase = b * HW;

    for (int chunk = 0; chunk < NCHUNK; ++chunk) {
        const int kbase = chunk * 32;

        // ---- stage B tile: rows rowquad*4-1 .. +4, cols colseg*32-1 .. +32 ----
        if (IN_MODE == 0) {
            for (int s = t; s < 1632; s += 256) {
                int icg = s & 3;
                int q   = s >> 2;
                int col = q % 34;
                int r   = q / 34;            // 0..11 = pl*6 + row
                int row = r % 6;
                int pl  = r / 6;
                int gh = rowquad * 4 + row - 1;
                int gw = colseg * 32 + col - 1;
                bf16x8 v;
#pragma unroll
                for (int i = 0; i < 8; ++i) v[i] = 0;
                if ((unsigned)gh < (unsigned)HH && (unsigned)gw < (unsigned)WW) {
                    const unsigned short* src = pl ? inL : inH;
                    v = *(const bf16x8*)(src + (size_t)(pixbase + gh * WW + gw) * ICP + kbase + icg * 8);
                }
                int ebyte = ((row * 40 + col) << 6) + (icg << 4);
                int byte  = (ebyte ^ ((col & 7) << 4)) + pl * 15360;
                *(bf16x8*)(lds_c + byte) = v;
            }
        } else {
            for (int s = t; s < 6528; s += 256) {
                int ic  = s / 204;
                int rem = s - ic * 204;
                int col = rem % 34;
                int row = rem / 34;
                int c   = kbase + ic;
                int gh = rowquad * 4 + row - 1;
                int gw = colseg * 32 + col - 1;
                float v = 0.f;
                if ((unsigned)gh < (unsigned)HH && (unsigned)gw < (unsigned)WW) {
                    int pix = gh * WW + gw;
                    if (c < 384)      v = ef[((size_t)(b * 384 + c)) * HW + pix];
                    else if (c < 386) v = f1[((size_t)(b * 2 + c - 384)) * HW + pix];
                    else if (c < 388) v = f2[((size_t)(b * 2 + c - 386)) * HW + pix];
                }
                unsigned short hs = f2bf(v);
                unsigned short ls = f2bf(v - bf2f(hs));
                int ebyte = (row * 40 + col) * 64 + ic * 2;
                int sw    = (col & 7) << 4;
                *(unsigned short*)(lds_c + (ebyte ^ sw))          = hs;
                *(unsigned short*)(lds_c + (ebyte ^ sw) + 15360)  = ls;
            }
        }
        __syncthreads();

        // ---- 9 taps: A double-buffered from global, B from LDS, 48 MFMA each ----
        bf16x8 Ah0[4], Al0[4], Ah1[4], Al1[4];
        LOADA(Ah0, Al0, 0);
#pragma unroll
        for (int tap = 0; tap < 9; ++tap) {
            const int ky = tap / 3, kx = tap % 3;
            bf16x8 Bh[4], Bl[4];
#pragma unroll
            for (int nf = 0; nf < 4; ++nf) {
                int rsub = nf >> 1, chf = nf & 1;
                int row  = ky + wn * 2 + rsub;
                int col  = kx + chf * 16 + lc;
                int byte = (((row * 40 + col) << 6) + (lr << 4)) ^ ((col & 7) << 4);
                Bh[nf] = *(const bf16x8*)(lds_c + byte);
                Bl[nf] = *(const bf16x8*)(lds_c + byte + 15360);
            }
            if (tap < 8) { LOADA(Ah1, Al1, tap + 1); }
            __builtin_amdgcn_s_setprio(1);
#pragma unroll
            for (int mf = 0; mf < 4; ++mf) {
#pragma unroll
                for (int nf = 0; nf < 4; ++nf) {
                    acc[mf][nf] = __builtin_amdgcn_mfma_f32_16x16x32_bf16(Al0[mf], Bh[nf], acc[mf][nf], 0, 0, 0);
                    acc[mf][nf] = __builtin_amdgcn_mfma_f32_16x16x32_bf16(Ah0[mf], Bl[nf], acc[mf][nf], 0, 0, 0);
                    acc[mf][nf] = __builtin_amdgcn_mfma_f32_16x16x32_bf16(Ah0[mf], Bh[nf], acc[mf][nf], 0, 0, 0);
                }
            }
            __builtin_amdgcn_s_setprio(0);
            if (tap < 8) {
#pragma unroll
                for (int mf = 0; mf < 4; ++mf) {
                    Ah0[mf] = Ah1[mf];
                    Al0[mf] = Al1[mf];
                }
            }
        }
        __syncthreads();
    }

    // ---- epilogue ----
#pragma unroll
    for (int mf = 0; mf < 4; ++mf) {
        const int ocb = wm * 64 + mf * 16 + lr * 4;      // local oc base (0..127)
#pragma unroll
        for (int nf = 0; nf < 4; ++nf) {
            const int rsub = nf >> 1, chf = nf & 1;
            const int h = rowquad * 4 + wn * 2 + rsub;
            const int w = colseg * 32 + chf * 16 + lc;
#pragma unroll
            for (int j = 0; j < 4; ++j) {
                float v = acc[mf][nf][j];
                if (EPI == 1) {
                    int oc = ocb + j;                    // mblk==0
                    v += bias[oc];
                    v = (v >= 0.f) ? v : 0.1f * v;
                    size_t idx = (size_t)(pixbase + h * WW + w) * 128 + oc;
                    unsigned short hs = f2bf(v);
                    outH[idx] = hs;
                    outL[idx] = f2bf(v - bf2f(hs));
                } else {
                    int oc = mblk * 128 + ocb + j;
                    if (oc < 432) {
                        v += bias[oc];
                        size_t idx = ((size_t)(b * 432 + oc)) * HW + h * WW + w;
                        if (oc < 288) {
                            float e  = __expf(2.f * v);
                            float th = 1.f - 2.f / (e + 1.f);
                            float off = 10.f * th;
                            const float* fl = (oc < 144) ? f1 : f2;
                            off += fl[((size_t)(b * 2 + (1 - (oc & 1)))) * HW + h * WW + w];
                            h3[idx] = __float2half(off);
                        } else {
                            h3[idx] = __float2half(1.f / (1.f + __expf(-v)));
                        }
                    }
                }
            }
        }
    }
}

// Weight transpose for deform: wT[(pair*8 + c)*128 + oc] = w[oc][g*8+c][k].
__global__ __launch_bounds__(256) void wtrans_k(const float* __restrict__ w, float* __restrict__ wT)
{
    int tid = blockIdx.x * 256 + threadIdx.x;
    if (tid < 128 * 128 * 9) {
        int oc   = tid & 127;
        int pc   = tid >> 7;
        int c    = pc & 7;
        int pair = pc >> 3;
        int g    = pair / 9, k = pair - g * 9;
        wT[tid] = w[((size_t)(oc * 128) + g * 8 + c) * 9 + k];
    }
}

__global__ __launch_bounds__(256) void init_out_k(const float* __restrict__ bias, float* __restrict__ out)
{
    int idx = blockIdx.x * 256 + threadIdx.x;
    if (idx < BB * 128 * HW) {
        int oc = (idx / HW) & 127;
        out[idx] = bias[oc];
    }
}

// Modulated deformable conv v2 (h3 fp16).
__global__ __launch_bounds__(256) void deform2_k(
    const float* __restrict__ x, const __half* __restrict__ h3,
    const float* __restrict__ wT, float* __restrict__ out)
{
    __shared__ int   s_y0[4][64], s_x0[4][64];
    __shared__ float s_wy[4][64], s_wx[4][64], s_m[4][64];
    __shared__ float s_val[4][8][64];

    const int t   = threadIdx.x;
    const int p   = t & 63;
    const int wv  = __builtin_amdgcn_readfirstlane(t >> 6);
    const int wb0 = blockIdx.x * 8, hb0 = blockIdx.y * 8;
    const int b   = blockIdx.z >> 2;
    const int gs  = blockIdx.z & 3;
    const int ho  = hb0 + (p >> 3), wo = wb0 + (p & 7);

    float acc[32];
#pragma unroll
    for (int o = 0; o < 32; ++o) acc[o] = 0.f;

    const int pairbase = gs * 36;
    const __half* hb = h3 + (size_t)b * 432 * HW + ho * WW + wo;

    for (int ch = 0; ch < 9; ++ch) {
        const int pb = pairbase + ch * 4;

        {
            int pair = pb + wv;
            int g = pair / 9, k = pair - (pair / 9) * 9;
            float dy = __half2float(hb[(size_t)(g * 18 + k * 2)     * HW]);
            float dx = __half2float(hb[(size_t)(g * 18 + k * 2 + 1) * HW]);
            float m  = __half2float(hb[(size_t)(288 + g * 9 + k)    * HW]);
            float py = dy + (float)(ho + k / 3 - 1);
            float px = dx + (float)(wo + (k % 3) - 1);
            float fy = floorf(py), fx = floorf(px);
            s_y0[wv][p] = (int)fy; s_x0[wv][p] = (int)fx;
            s_wy[wv][p] = py - fy; s_wx[wv][p] = px - fx;
            s_m[wv][p]  = m;
        }
        __syncthreads();

        #pragma unroll
        for (int i = 0; i < 8; ++i) {
            int m4 = i * 4 + wv;
            int j  = m4 >> 3, c = m4 & 7;
            int pair = pb + j;
            int g  = pair / 9;
            const float* xp = x + ((size_t)(b * 128) + g * 8 + c) * HW;
            int   yy0 = s_y0[j][p], xx0 = s_x0[j][p];
            float wy  = s_wy[j][p], wx  = s_wx[j][p];
            float v00 = 0.f, v01 = 0.f, v10 = 0.f, v11 = 0.f;
            bool x0ok = (unsigned)xx0       < (unsigned)WW;
            bool x1ok = (unsigned)(xx0 + 1) < (unsigned)WW;
            if ((unsigned)yy0 < (unsigned)HH) {
                const float* r = xp + yy0 * WW;
                if (x0ok) v00 = r[xx0];
                if (x1ok) v01 = r[xx0 + 1];
            }
            if ((unsigned)(yy0 + 1) < (unsigned)HH) {
                const float* r = xp + (yy0 + 1) * WW;
                if (x0ok) v10 = r[xx0];
                if (x1ok) v11 = r[xx0 + 1];
            }
            float bi = (1.f - wy) * ((1.f - wx) * v00 + wx * v01)
                     +        wy  * ((1.f - wx) * v10 + wx * v11);
            s_val[j][c][p] = bi * s_m[j][p];
        }
        __syncthreads();

        const float* wtb = wT + (size_t)pb * 8 * 128 + wv * 32;
        #pragma unroll
        for (int j = 0; j < 4; ++j) {
            #pragma unroll
            for (int c = 0; c < 8; ++c) {
                float v = s_val[j][c][p];
                const float* wp = wtb + (j * 8 + c) * 128;
                #pragma unroll
                for (int o = 0; o < 32; ++o)
                    acc[o] = fmaf(v, wp[o], acc[o]);
            }
        }
    }

    float* op = out + ((size_t)(b * 128) + wv * 32) * HW + ho * WW + wo;
#pragma unroll
    for (int o = 0; o < 32; ++o)
        atomicAdd(op + (size_t)o * HW, acc[o]);
}

extern "C" void kernel_launch(void* const* d_in, const int* in_sizes, int n_in,
                              void* d_out, int out_size, void* d_ws, size_t ws_size,
                              hipStream_t stream)
{
    const float* x    = (const float*)d_in[0];
    const float* ef   = (const float*)d_in[1];
    const float* f1   = (const float*)d_in[2];
    const float* f2   = (const float*)d_in[3];
    const float* wgt  = (const float*)d_in[4];
    const float* bias = (const float*)d_in[5];
    const float* cw0  = (const float*)d_in[6];
    const float* cb0  = (const float*)d_in[7];
    const float* cw1  = (const float*)d_in[8];
    const float* cb1  = (const float*)d_in[9];
    const float* cw2  = (const float*)d_in[10];
    const float* cb2  = (const float*)d_in[11];
    const float* cw3  = (const float*)d_in[12];
    const float* cb3  = (const float*)d_in[13];

    float* outp = (float*)d_out;
    char*  ws   = (char*)d_ws;

    // ---- ws layout (bytes) ----
    float*          wT   = (float*)         (ws + 0);           // 589,824
    unsigned short* W0h  = (unsigned short*)(ws + 589824);      // 958,464
    unsigned short* W0l  = (unsigned short*)(ws + 1548288);
    unsigned short* W1h  = (unsigned short*)(ws + 2506752);     // 294,912
    unsigned short* W1l  = (unsigned short*)(ws + 2801664);
    unsigned short* W2h  = (unsigned short*)(ws + 3096576);
    unsigned short* W2l  = (unsigned short*)(ws + 3391488);
    unsigned short* W3h  = (unsigned short*)(ws + 3686400);     // 1,179,648
    unsigned short* W3l  = (unsigned short*)(ws + 4866048);
    unsigned short* o0H  = (unsigned short*)(ws + 6045696);     // 7,864,320 each
    unsigned short* o0L  = (unsigned short*)(ws + 13910016);
    unsigned short* o1H  = (unsigned short*)(ws + 21774336);
    unsigned short* o1L  = (unsigned short*)(ws + 29638656);
    unsigned short* o2H  = (unsigned short*)(ws + 37502976);
    unsigned short* o2L  = (unsigned short*)(ws + 45367296);
    // h3 (fp16, 26,542,080 B) overlays dead o0/o1 region
    __half*         h3   = (__half*)        (ws + 6045696);

    dim3 blk(256);

    // weight prep
    hipLaunchKernelGGL(wtrans_k, dim3((128 * 128 * 9 + 255) / 256), blk, 0, stream, wgt, wT);
    hipLaunchKernelGGL(wsplit_k, dim3((9 * 128 * 416 + 255) / 256), blk, 0, stream, cw0, 128, 388, 128, 416, W0h, W0l);
    hipLaunchKernelGGL(wsplit_k, dim3((9 * 128 * 128 + 255) / 256), blk, 0, stream, cw1, 128, 128, 128, 128, W1h, W1l);
    hipLaunchKernelGGL(wsplit_k, dim3((9 * 128 * 128 + 255) / 256), blk, 0, stream, cw2, 128, 128, 128, 128, W2h, W2l);
    hipLaunchKernelGGL(wsplit_k, dim3((9 * 512 * 128 + 255) / 256), blk, 0, stream, cw3, 432, 128, 512, 128, W3h, W3l);

    dim3 gc (5, 24, BB);         // conv0/1/2: 4 rows x 32 cols tiles
    dim3 gc3(5, 24, BB * 4);     // conv3 (OCP=512 -> 4 m-blocks)

    // conv0: concat fp32 -> o0 (lrelu, NHWC hi/lo)
    hipLaunchKernelGGL((conv_mfma<1, 1, 13, 416, 128>), gc, blk, 0, stream,
                       ef, f1, f2, nullptr, nullptr, W0h, W0l, cb0, o0H, o0L, nullptr);
    // conv1: o0 -> o1
    hipLaunchKernelGGL((conv_mfma<0, 1, 4, 128, 128>), gc, blk, 0, stream,
                       nullptr, nullptr, nullptr, o0H, o0L, W1h, W1l, cb1, o1H, o1L, nullptr);
    // conv2: o1 -> o2
    hipLaunchKernelGGL((conv_mfma<0, 1, 4, 128, 128>), gc, blk, 0, stream,
                       nullptr, nullptr, nullptr, o1H, o1L, W2h, W2l, cb2, o2H, o2L, nullptr);
    // conv3: o2 -> h3 (fp16, offset/mask epilogue)  [h3 overlays dead o0/o1]
    hipLaunchKernelGGL((conv_mfma<0, 2, 4, 128, 512>), gc3, blk, 0, stream,
                       nullptr, f1, f2, o2H, o2L, W3h, W3l, cb3, nullptr, nullptr, h3);

    // out = bias; deform partials atomicAdd into it
    hipLaunchKernelGGL(init_out_k, dim3((BB * 128 * HW + 255) / 256), blk, 0, stream, bias, outp);
    hipLaunchKernelGGL(deform2_k, dim3(WW / 8, HH / 8, BB * 4), blk, 0, stream, x, h3, wT, outp);
}